// Round 1
// baseline (1668.056 us; speedup 1.0000x reference)
//
#include <hip/hip_runtime.h>

#define S_LEN 4096
#define BATCH 4
#define DMODEL 1040
#define NH 16
#define FEAT 32
#define HD 65  // 2*FEAT+1

// ---------------- generic tiled fp32 GEMM: C[M,N] = A[M,K] @ B[K,N], all row-major ----
#define BM 64
#define BN 64
#define BK 16

__global__ __launch_bounds__(256) void gemm_rr(const float* __restrict__ A,
                                               const float* __restrict__ B,
                                               float* __restrict__ C,
                                               int M, int N, int K) {
  const int n0 = blockIdx.x * BN;
  const int m0 = blockIdx.y * BM;
  __shared__ float As[BK][BM];
  __shared__ float Bs[BK][BN];
  const int tid = threadIdx.x;
  const int tx = tid & 15, ty = tid >> 4;
  const int ar = tid >> 2;         // 0..63  (m within tile)
  const int ac = (tid & 3) * 4;    // 0,4,8,12 (k within tile)
  const int br = tid >> 4;         // 0..15  (k within tile)
  const int bc = (tid & 15) * 4;   // 0..60  (n within tile)
  float acc[4][4] = {};
  for (int k0 = 0; k0 < K; k0 += BK) {
    float4 av = *reinterpret_cast<const float4*>(&A[(size_t)(m0 + ar) * K + (k0 + ac)]);
    As[ac + 0][ar] = av.x;
    As[ac + 1][ar] = av.y;
    As[ac + 2][ar] = av.z;
    As[ac + 3][ar] = av.w;
    float4 bv = make_float4(0.f, 0.f, 0.f, 0.f);
    if (n0 + bc < N)  // N % 4 == 0 so a float4 is all-valid or all-invalid
      bv = *reinterpret_cast<const float4*>(&B[(size_t)(k0 + br) * N + (n0 + bc)]);
    *reinterpret_cast<float4*>(&Bs[br][bc]) = bv;
    __syncthreads();
#pragma unroll
    for (int kk = 0; kk < BK; ++kk) {
      float a[4], b[4];
#pragma unroll
      for (int i = 0; i < 4; ++i) a[i] = As[kk][ty * 4 + i];
#pragma unroll
      for (int j = 0; j < 4; ++j) b[j] = Bs[kk][tx * 4 + j];
#pragma unroll
      for (int i = 0; i < 4; ++i)
#pragma unroll
        for (int j = 0; j < 4; ++j) acc[i][j] += a[i] * b[j];
    }
    __syncthreads();
  }
  if (n0 + tx * 4 < N) {
#pragma unroll
    for (int i = 0; i < 4; ++i) {
      float4 cv = make_float4(acc[i][0], acc[i][1], acc[i][2], acc[i][3]);
      *reinterpret_cast<float4*>(&C[(size_t)(m0 + ty * 4 + i) * N + (n0 + tx * 4)]) = cv;
    }
  }
}

// ---- GEMM with A stored as At[BATCH][K][S_LEN] (transposed per batch): C[M,N] row-major
__global__ __launch_bounds__(256) void gemm_tA(const float* __restrict__ At,
                                               const float* __restrict__ B,
                                               float* __restrict__ C,
                                               int N, int K) {
  const int n0 = blockIdx.x * BN;
  const int m0 = blockIdx.y * BM;
  const int bb = m0 >> 12;          // batch index (S_LEN=4096, BM divides it)
  const int nb = m0 & (S_LEN - 1);  // seq position base
  __shared__ float As[BK][BM];
  __shared__ float Bs[BK][BN];
  const int tid = threadIdx.x;
  const int tx = tid & 15, ty = tid >> 4;
  const int akk = tid >> 4;        // 0..15 (k)
  const int ann = (tid & 15) * 4;  // 0..60 (m)
  const int br = tid >> 4;
  const int bc = (tid & 15) * 4;
  float acc[4][4] = {};
  for (int k0 = 0; k0 < K; k0 += BK) {
    float4 av = *reinterpret_cast<const float4*>(
        &At[((size_t)(bb * K + k0 + akk)) * S_LEN + (nb + ann)]);
    *reinterpret_cast<float4*>(&As[akk][ann]) = av;
    float4 bv = make_float4(0.f, 0.f, 0.f, 0.f);
    if (n0 + bc < N)
      bv = *reinterpret_cast<const float4*>(&B[(size_t)(k0 + br) * N + (n0 + bc)]);
    *reinterpret_cast<float4*>(&Bs[br][bc]) = bv;
    __syncthreads();
#pragma unroll
    for (int kk = 0; kk < BK; ++kk) {
      float a[4], b[4];
#pragma unroll
      for (int i = 0; i < 4; ++i) a[i] = As[kk][ty * 4 + i];
#pragma unroll
      for (int j = 0; j < 4; ++j) b[j] = Bs[kk][tx * 4 + j];
#pragma unroll
      for (int i = 0; i < 4; ++i)
#pragma unroll
        for (int j = 0; j < 4; ++j) acc[i][j] += a[i] * b[j];
    }
    __syncthreads();
  }
  if (n0 + tx * 4 < N) {
#pragma unroll
    for (int i = 0; i < 4; ++i) {
      float4 cv = make_float4(acc[i][0], acc[i][1], acc[i][2], acc[i][3]);
      *reinterpret_cast<float4*>(&C[(size_t)(m0 + ty * 4 + i) * N + (n0 + tx * 4)]) = cv;
    }
  }
}

// ---------------- kv state: per (b,h,split) partial of phi(k)^T @ v and column sums ----
// kvpart[(split*64+bh)*4225 + d*65 + e], kspart[(split*64+bh)*65 + e]
__global__ __launch_bounds__(256) void kv_kernel(const float* __restrict__ kbuf,
                                                 const float* __restrict__ vbuf,
                                                 float* __restrict__ kvpart,
                                                 float* __restrict__ kspart) {
  const int bh = blockIdx.x;    // 0..63
  const int split = blockIdx.y; // 0..7
  const int b = bh >> 4, h = bh & 15;
  __shared__ float ks[64][68];  // phi(k) tile (65 valid cols, padded)
  __shared__ float vs[64][68];  // v tile
  const int tid = threadIdx.x;
  // tile ownership: 17x17 = 289 4x4 tiles over the 65x65 (padded to 68x68) output
  const int t0 = tid;
  const int t1 = 256 + tid;  // valid only for tid < 33
  const int d00 = (t0 / 17) * 4, e00 = (t0 % 17) * 4;
  const int d10 = (t1 / 17) * 4, e10 = (t1 % 17) * 4;
  float acc0[16] = {};
  float acc1[16] = {};
  float kcol = 0.f;  // ksum partial for column tid (tid < 65)

  for (int chunk = 0; chunk < 8; ++chunk) {
    const int nb = split * 512 + chunk * 64;
    for (int idx = tid; idx < 64 * 65; idx += 256) {
      const int r = idx / 65, d = idx % 65;
      const int n = nb + r;
      float val;
      if (d == 0) {
        val = 1.f;
      } else if (d <= 32) {
        val = kbuf[((size_t)(b * S_LEN + n)) * 512 + h * 32 + (d - 1)];
      } else {
        float x = kbuf[((size_t)(b * S_LEN + n)) * 512 + h * 32 + (d - 33)];
        val = 0.5f * x * x;
      }
      ks[r][d] = val;
      vs[r][d] = vbuf[((size_t)(b * S_LEN + n)) * 1040 + h * 65 + d];
    }
    __syncthreads();
    for (int r = 0; r < 64; ++r) {
      float a[4], v[4];
#pragma unroll
      for (int i = 0; i < 4; ++i) a[i] = ks[r][d00 + i];
#pragma unroll
      for (int j = 0; j < 4; ++j) v[j] = vs[r][e00 + j];
#pragma unroll
      for (int i = 0; i < 4; ++i)
#pragma unroll
        for (int j = 0; j < 4; ++j) acc0[i * 4 + j] += a[i] * v[j];
    }
    if (tid < 33) {
      for (int r = 0; r < 64; ++r) {
        float a[4], v[4];
#pragma unroll
        for (int i = 0; i < 4; ++i) a[i] = ks[r][d10 + i];
#pragma unroll
        for (int j = 0; j < 4; ++j) v[j] = vs[r][e10 + j];
#pragma unroll
        for (int i = 0; i < 4; ++i)
#pragma unroll
          for (int j = 0; j < 4; ++j) acc1[i * 4 + j] += a[i] * v[j];
      }
    }
    if (tid < 65) {
      float s = 0.f;
      for (int r = 0; r < 64; ++r) s += ks[r][tid];
      kcol += s;
    }
    __syncthreads();
  }

  float* kvp = kvpart + ((size_t)split * 64 + bh) * 4225;
#pragma unroll
  for (int i = 0; i < 4; ++i)
#pragma unroll
    for (int j = 0; j < 4; ++j) {
      int d = d00 + i, e = e00 + j;
      if (d < 65 && e < 65) kvp[d * 65 + e] = acc0[i * 4 + j];
    }
  if (tid < 33) {
#pragma unroll
    for (int i = 0; i < 4; ++i)
#pragma unroll
      for (int j = 0; j < 4; ++j) {
        int d = d10 + i, e = e10 + j;
        if (d < 65 && e < 65) kvp[d * 65 + e] = acc1[i * 4 + j];
      }
  }
  if (tid < 65) kspart[((size_t)split * 64 + bh) * 65 + tid] = kcol;
}

// ---------------- reduce the 8 split-partials ----------------
__global__ __launch_bounds__(256) void kv_reduce(const float* __restrict__ kvpart,
                                                 const float* __restrict__ kspart,
                                                 float* __restrict__ kv,
                                                 float* __restrict__ ksum) {
  const int NKV = 64 * 4225;
  const int NKS = 64 * 65;
  int i = blockIdx.x * 256 + threadIdx.x;
  if (i < NKV) {
    float s = 0.f;
#pragma unroll
    for (int p = 0; p < 8; ++p) s += kvpart[(size_t)p * NKV + i];
    kv[i] = s;
  } else if (i < NKV + NKS) {
    int j = i - NKV;
    float s = 0.f;
#pragma unroll
    for (int p = 0; p < 8; ++p) s += kspart[p * NKS + j];
    ksum[j] = s;
  }
}

// ---------------- phi(q) @ kv, normalize, mask; write transposed [B][1040][S] ----------
__global__ __launch_bounds__(256) void qkv_kernel(const float* __restrict__ qbuf,
                                                  const float* __restrict__ kv,
                                                  const float* __restrict__ ksum,
                                                  const int* __restrict__ mask,
                                                  float* __restrict__ attn_t) {
  const int nchunk = blockIdx.x;  // 0..15
  const int bh = blockIdx.y;      // 0..63
  const int b = bh >> 4, h = bh & 15;
  __shared__ float kvs[4225];
  __shared__ float kss[65];
  const int tid = threadIdx.x;
  const float* kvp = kv + (size_t)bh * 4225;
  for (int i = tid; i < 4225; i += 256) kvs[i] = kvp[i];
  if (tid < 65) kss[tid] = ksum[bh * 65 + tid];
  __syncthreads();

  const int n = nchunk * 256 + tid;
  const size_t qoff = ((size_t)(b * S_LEN + n)) * 512 + h * 32;
  float q[32], qq[32];
#pragma unroll
  for (int f4 = 0; f4 < 8; ++f4) {
    float4 v = *reinterpret_cast<const float4*>(&qbuf[qoff + f4 * 4]);
    q[f4 * 4 + 0] = v.x; qq[f4 * 4 + 0] = 0.5f * v.x * v.x;
    q[f4 * 4 + 1] = v.y; qq[f4 * 4 + 1] = 0.5f * v.y * v.y;
    q[f4 * 4 + 2] = v.z; qq[f4 * 4 + 2] = 0.5f * v.z * v.z;
    q[f4 * 4 + 3] = v.w; qq[f4 * 4 + 3] = 0.5f * v.w * v.w;
  }
  float qsum = 1.f;
#pragma unroll
  for (int f = 0; f < 32; ++f) qsum += q[f] + qq[f];
  const int m = mask[b * S_LEN + n];
  float* outp = attn_t + ((size_t)b * 1040 + h * 65) * S_LEN + n;
  for (int e = 0; e < 65; ++e) {
    float acc = kvs[e];  // d = 0 (the "1" feature)
#pragma unroll
    for (int f = 0; f < 32; ++f) {
      acc += q[f] * kvs[(1 + f) * 65 + e];
      acc += qq[f] * kvs[(33 + f) * 65 + e];
    }
    float z = qsum * kss[e] + 1e-9f;
    float o = (m == 0) ? 0.f : acc / z;
    outp[(size_t)e * S_LEN] = o;
  }
}

extern "C" void kernel_launch(void* const* d_in, const int* in_sizes, int n_in,
                              void* d_out, int out_size, void* d_ws, size_t ws_size,
                              hipStream_t stream) {
  const float* hs = (const float*)d_in[0];
  const int* mask = (const int*)d_in[1];
  const float* Wq = (const float*)d_in[2];
  const float* Wk = (const float*)d_in[3];
  const float* Wv = (const float*)d_in[4];
  const float* Wo = (const float*)d_in[5];
  float* out = (float*)d_out;
  float* ws = (float*)d_ws;

  const int M = BATCH * S_LEN;  // 16384
  const size_t KQ_SZ = (size_t)M * 512;
  const size_t V_SZ = (size_t)M * 1040;
  const size_t KV_SZ = 64 * 4225;
  const size_t KS_SZ = 64 * 65;

  float* kqbuf = ws;                  // k proj, later reused for q proj
  float* vbuf = kqbuf + KQ_SZ;        // v proj, later reused as attn_t
  float* kv = vbuf + V_SZ;
  float* ksum = kv + KV_SZ;
  float* kvpart = ksum + KS_SZ;       // 8 * KV_SZ
  float* kspart = kvpart + 8 * KV_SZ; // 8 * KS_SZ

  dim3 blk(256);

  // k and v projections
  gemm_rr<<<dim3(512 / BN, M / BM), blk, 0, stream>>>(hs, Wk, kqbuf, M, 512, DMODEL);
  gemm_rr<<<dim3((1040 + BN - 1) / BN, M / BM), blk, 0, stream>>>(hs, Wv, vbuf, M, 1040, DMODEL);

  // kv state partials + reduce
  kv_kernel<<<dim3(64, 8), blk, 0, stream>>>(kqbuf, vbuf, kvpart, kspart);
  kv_reduce<<<dim3((64 * 4225 + 64 * 65 + 255) / 256), blk, 0, stream>>>(kvpart, kspart, kv, ksum);

  // q projection (reuses kqbuf)
  gemm_rr<<<dim3(512 / BN, M / BM), blk, 0, stream>>>(hs, Wq, kqbuf, M, 512, DMODEL);

  // phi(q) @ kv, normalize, mask -> attn_t (reuses vbuf, transposed layout)
  qkv_kernel<<<dim3(16, 64), blk, 0, stream>>>(kqbuf, kv, ksum, mask, vbuf);

  // output projection
  gemm_tA<<<dim3((1040 + BN - 1) / BN, M / BM), blk, 0, stream>>>(vbuf, Wo, out, 1040, DMODEL);
}

// Round 2
// 1331.772 us; speedup vs baseline: 1.2525x; 1.2525x over previous
//
#include <hip/hip_runtime.h>
#include <hip/hip_bf16.h>

typedef unsigned short ushort_t;

#define S_LEN 4096
#define BATCH 4
#define DMODEL 1040
#define KPAD 1056          // 1040 padded to 33*32
#define NPADW 1152         // 1040 padded to 9*128 (Wt rows)
#define M_TOK 16384        // BATCH*S_LEN

using f32x4 = __attribute__((ext_vector_type(4))) float;
using bf16x8 = __attribute__((ext_vector_type(8))) __bf16;

__device__ __forceinline__ void splitf(float a, ushort_t& h, ushort_t& l) {
  __hip_bfloat16 bh = __float2bfloat16(a);
  float r = a - __bfloat162float(bh);
  __hip_bfloat16 bl = __float2bfloat16(r);
  h = __builtin_bit_cast(ushort_t, bh);
  l = __builtin_bit_cast(ushort_t, bl);
}

typedef const __attribute__((address_space(1))) unsigned int* gas_u32p;
typedef __attribute__((address_space(3))) unsigned int* las_u32p;
__device__ __forceinline__ void gload_lds16(const ushort_t* g, ushort_t* l) {
  __builtin_amdgcn_global_load_lds((gas_u32p)g, (las_u32p)l, 16, 0, 0);
}

// ---------------- split hs [M][1040] f32 -> hi/lo bf16 [M][KPAD] (zero-padded) --------
__global__ __launch_bounds__(256) void split_hs_kernel(const float* __restrict__ hs,
                                                       ushort_t* __restrict__ hh,
                                                       ushort_t* __restrict__ hl) {
  const int C8 = KPAD / 8;  // 132
  int idx = blockIdx.x * 256 + threadIdx.x;
  if (idx >= M_TOK * C8) return;
  int row = idx / C8, col = (idx % C8) * 8;
  ushort_t h[8], l[8];
  if (col < DMODEL) {
    const float* p = &hs[(size_t)row * DMODEL + col];
#pragma unroll
    for (int j = 0; j < 8; ++j) splitf(p[j], h[j], l[j]);
  } else {
#pragma unroll
    for (int j = 0; j < 8; ++j) { h[j] = 0; l[j] = 0; }
  }
  size_t o = (size_t)row * KPAD + col;
#pragma unroll
  for (int j = 0; j < 8; ++j) { hh[o + j] = h[j]; hl[o + j] = l[j]; }
}

// ------------- transpose+split W [1040][1040] -> Wt hi/lo [NPADW][KPAD] ---------------
__global__ __launch_bounds__(256) void split_w_kernel(const float* __restrict__ W,
                                                      ushort_t* __restrict__ Wth,
                                                      ushort_t* __restrict__ Wtl) {
  const int C8 = KPAD / 8;
  int idx = blockIdx.x * 256 + threadIdx.x;
  if (idx >= NPADW * C8) return;
  int n = idx / C8, k = (idx % C8) * 8;
  ushort_t h[8], l[8];
  if (n < DMODEL && k < DMODEL) {
#pragma unroll
    for (int j = 0; j < 8; ++j) splitf(W[(size_t)(k + j) * DMODEL + n], h[j], l[j]);
  } else {
#pragma unroll
    for (int j = 0; j < 8; ++j) { h[j] = 0; l[j] = 0; }
  }
  size_t o = (size_t)n * KPAD + k;
#pragma unroll
  for (int j = 0; j < 8; ++j) { Wth[o + j] = h[j]; Wtl[o + j] = l[j]; }
}

// ------- split-bf16 MFMA GEMM: C[M][N] = A[M][K] @ Bt[N][K]^T  (A,B pre-split) --------
// 128x128 tile, BK=32, global_load_lds staging with XOR chunk swizzle.
__global__ __launch_bounds__(256) void gemm_split(const ushort_t* __restrict__ Ahg,
                                                  const ushort_t* __restrict__ Alg,
                                                  const ushort_t* __restrict__ Bhg,
                                                  const ushort_t* __restrict__ Blg,
                                                  float* __restrict__ C, int N) {
  __shared__ ushort_t Ah[4096], Al[4096], Bh[4096], Bl[4096];
  const int t = threadIdx.x;
  const int w = t >> 6, l = t & 63;
  const int m0 = blockIdx.y * 128, n0 = blockIdx.x * 128;
  const int wm = w >> 1, wn = w & 1;
  const int row16 = l & 15, g = l >> 4;

  f32x4 acc[4][4];
#pragma unroll
  for (int m = 0; m < 4; ++m)
#pragma unroll
    for (int n = 0; n < 4; ++n) acc[m][n] = (f32x4){0.f, 0.f, 0.f, 0.f};

  // staging chunk mapping (constant across k-steps)
  const int chunk0 = (w * 2 + 0) * 64 + l;
  const int chunk1 = (w * 2 + 1) * 64 + l;
  const int r0 = chunk0 >> 2, r1 = chunk1 >> 2;
  const int ch0 = (chunk0 & 3) ^ ((r0 ^ (r0 >> 2)) & 3);
  const int ch1 = (chunk1 & 3) ^ ((r1 ^ (r1 >> 2)) & 3);

  for (int k0 = 0; k0 < KPAD; k0 += 32) {
    {
      const size_t ga0 = (size_t)(m0 + r0) * KPAD + k0 + ch0 * 8;
      const size_t gb0 = (size_t)(n0 + r0) * KPAD + k0 + ch0 * 8;
      const size_t ga1 = (size_t)(m0 + r1) * KPAD + k0 + ch1 * 8;
      const size_t gb1 = (size_t)(n0 + r1) * KPAD + k0 + ch1 * 8;
      gload_lds16(Ahg + ga0, &Ah[chunk0 * 8]);
      gload_lds16(Alg + ga0, &Al[chunk0 * 8]);
      gload_lds16(Bhg + gb0, &Bh[chunk0 * 8]);
      gload_lds16(Blg + gb0, &Bl[chunk0 * 8]);
      gload_lds16(Ahg + ga1, &Ah[chunk1 * 8]);
      gload_lds16(Alg + ga1, &Al[chunk1 * 8]);
      gload_lds16(Bhg + gb1, &Bh[chunk1 * 8]);
      gload_lds16(Blg + gb1, &Bl[chunk1 * 8]);
    }
    __syncthreads();
    bf16x8 fah[4], fal[4], fbh[4], fbl[4];
#pragma unroll
    for (int f = 0; f < 4; ++f) {
      const int ra = wm * 64 + f * 16 + row16;
      const int ca = (g ^ ((ra ^ (ra >> 2)) & 3)) << 3;
      fah[f] = *(const bf16x8*)&Ah[ra * 32 + ca];
      fal[f] = *(const bf16x8*)&Al[ra * 32 + ca];
      const int rb = wn * 64 + f * 16 + row16;
      const int cb = (g ^ ((rb ^ (rb >> 2)) & 3)) << 3;
      fbh[f] = *(const bf16x8*)&Bh[rb * 32 + cb];
      fbl[f] = *(const bf16x8*)&Bl[rb * 32 + cb];
    }
#pragma unroll
    for (int m = 0; m < 4; ++m)
#pragma unroll
      for (int n = 0; n < 4; ++n) {
        acc[m][n] = __builtin_amdgcn_mfma_f32_16x16x32_bf16(fah[m], fbh[n], acc[m][n], 0, 0, 0);
        acc[m][n] = __builtin_amdgcn_mfma_f32_16x16x32_bf16(fal[m], fbh[n], acc[m][n], 0, 0, 0);
        acc[m][n] = __builtin_amdgcn_mfma_f32_16x16x32_bf16(fah[m], fbl[n], acc[m][n], 0, 0, 0);
      }
    __syncthreads();
  }
#pragma unroll
  for (int m = 0; m < 4; ++m)
#pragma unroll
    for (int n = 0; n < 4; ++n) {
      const int col = n0 + wn * 64 + n * 16 + row16;
      if (col < N) {
        const int rowb = m0 + wm * 64 + m * 16 + g * 4;
#pragma unroll
        for (int i = 0; i < 4; ++i) C[(size_t)(rowb + i) * N + col] = acc[m][n][i];
      }
    }
}

// ---------------- fp32 tiled GEMM (q/k projections): C = A[M,K] @ B[K,N] --------------
#define BM 64
#define BN 64
#define BK 16

__global__ __launch_bounds__(256) void gemm_rr(const float* __restrict__ A,
                                               const float* __restrict__ B,
                                               float* __restrict__ C,
                                               int M, int N, int K) {
  const int n0 = blockIdx.x * BN;
  const int m0 = blockIdx.y * BM;
  __shared__ float As[BK][BM];
  __shared__ float Bs[BK][BN];
  const int tid = threadIdx.x;
  const int tx = tid & 15, ty = tid >> 4;
  const int ar = tid >> 2;
  const int ac = (tid & 3) * 4;
  const int br = tid >> 4;
  const int bc = (tid & 15) * 4;
  float acc[4][4] = {};
  for (int k0 = 0; k0 < K; k0 += BK) {
    float4 av = *reinterpret_cast<const float4*>(&A[(size_t)(m0 + ar) * K + (k0 + ac)]);
    As[ac + 0][ar] = av.x;
    As[ac + 1][ar] = av.y;
    As[ac + 2][ar] = av.z;
    As[ac + 3][ar] = av.w;
    float4 bv = *reinterpret_cast<const float4*>(&B[(size_t)(k0 + br) * N + (n0 + bc)]);
    *reinterpret_cast<float4*>(&Bs[br][bc]) = bv;
    __syncthreads();
#pragma unroll
    for (int kk = 0; kk < BK; ++kk) {
      float a[4], b[4];
#pragma unroll
      for (int i = 0; i < 4; ++i) a[i] = As[kk][ty * 4 + i];
#pragma unroll
      for (int j = 0; j < 4; ++j) b[j] = Bs[kk][tx * 4 + j];
#pragma unroll
      for (int i = 0; i < 4; ++i)
#pragma unroll
        for (int j = 0; j < 4; ++j) acc[i][j] += a[i] * b[j];
    }
    __syncthreads();
  }
#pragma unroll
  for (int i = 0; i < 4; ++i) {
    float4 cv = make_float4(acc[i][0], acc[i][1], acc[i][2], acc[i][3]);
    *reinterpret_cast<float4*>(&C[(size_t)(m0 + ty * 4 + i) * N + (n0 + tx * 4)]) = cv;
  }
}

// ---------------- kv state: per (b,h,split) partial of phi(k)^T @ v ----
__global__ __launch_bounds__(256) void kv_kernel(const float* __restrict__ kbuf,
                                                 const float* __restrict__ vbuf,
                                                 float* __restrict__ kvpart,
                                                 float* __restrict__ kspart) {
  const int bh = blockIdx.x;
  const int split = blockIdx.y;
  const int b = bh >> 4, h = bh & 15;
  __shared__ float ks[64][68];
  __shared__ float vs[64][68];
  const int tid = threadIdx.x;
  const int t0 = tid;
  const int t1 = 256 + tid;
  const int d00 = (t0 / 17) * 4, e00 = (t0 % 17) * 4;
  const int d10 = (t1 / 17) * 4, e10 = (t1 % 17) * 4;
  float acc0[16] = {};
  float acc1[16] = {};
  float kcol = 0.f;

  for (int chunk = 0; chunk < 8; ++chunk) {
    const int nb = split * 512 + chunk * 64;
    for (int idx = tid; idx < 64 * 65; idx += 256) {
      const int r = idx / 65, d = idx % 65;
      const int n = nb + r;
      float val;
      if (d == 0) {
        val = 1.f;
      } else if (d <= 32) {
        val = kbuf[((size_t)(b * S_LEN + n)) * 512 + h * 32 + (d - 1)];
      } else {
        float x = kbuf[((size_t)(b * S_LEN + n)) * 512 + h * 32 + (d - 33)];
        val = 0.5f * x * x;
      }
      ks[r][d] = val;
      vs[r][d] = vbuf[((size_t)(b * S_LEN + n)) * 1040 + h * 65 + d];
    }
    __syncthreads();
    for (int r = 0; r < 64; ++r) {
      float a[4], v[4];
#pragma unroll
      for (int i = 0; i < 4; ++i) a[i] = ks[r][d00 + i];
#pragma unroll
      for (int j = 0; j < 4; ++j) v[j] = vs[r][e00 + j];
#pragma unroll
      for (int i = 0; i < 4; ++i)
#pragma unroll
        for (int j = 0; j < 4; ++j) acc0[i * 4 + j] += a[i] * v[j];
    }
    if (tid < 33) {
      for (int r = 0; r < 64; ++r) {
        float a[4], v[4];
#pragma unroll
        for (int i = 0; i < 4; ++i) a[i] = ks[r][d10 + i];
#pragma unroll
        for (int j = 0; j < 4; ++j) v[j] = vs[r][e10 + j];
#pragma unroll
        for (int i = 0; i < 4; ++i)
#pragma unroll
          for (int j = 0; j < 4; ++j) acc1[i * 4 + j] += a[i] * v[j];
      }
    }
    if (tid < 65) {
      float s = 0.f;
      for (int r = 0; r < 64; ++r) s += ks[r][tid];
      kcol += s;
    }
    __syncthreads();
  }

  float* kvp = kvpart + ((size_t)split * 64 + bh) * 4225;
#pragma unroll
  for (int i = 0; i < 4; ++i)
#pragma unroll
    for (int j = 0; j < 4; ++j) {
      int d = d00 + i, e = e00 + j;
      if (d < 65 && e < 65) kvp[d * 65 + e] = acc0[i * 4 + j];
    }
  if (tid < 33) {
#pragma unroll
    for (int i = 0; i < 4; ++i)
#pragma unroll
      for (int j = 0; j < 4; ++j) {
        int d = d10 + i, e = e10 + j;
        if (d < 65 && e < 65) kvp[d * 65 + e] = acc1[i * 4 + j];
      }
  }
  if (tid < 65) kspart[((size_t)split * 64 + bh) * 65 + tid] = kcol;
}

__global__ __launch_bounds__(256) void kv_reduce(const float* __restrict__ kvpart,
                                                 const float* __restrict__ kspart,
                                                 float* __restrict__ kv,
                                                 float* __restrict__ ksum) {
  const int NKV = 64 * 4225;
  const int NKS = 64 * 65;
  int i = blockIdx.x * 256 + threadIdx.x;
  if (i < NKV) {
    float s = 0.f;
#pragma unroll
    for (int p = 0; p < 8; ++p) s += kvpart[(size_t)p * NKV + i];
    kv[i] = s;
  } else if (i < NKV + NKS) {
    int j = i - NKV;
    float s = 0.f;
#pragma unroll
    for (int p = 0; p < 8; ++p) s += kspart[p * NKS + j];
    ksum[j] = s;
  }
}

// ------- phi(q)@kv, normalize, mask; emit attn as split bf16 [M][KPAD] ---------------
__global__ __launch_bounds__(256) void qkv_kernel(const float* __restrict__ qbuf,
                                                  const float* __restrict__ kv,
                                                  const float* __restrict__ ksum,
                                                  const int* __restrict__ mask,
                                                  ushort_t* __restrict__ ath,
                                                  ushort_t* __restrict__ atl) {
  const int nchunk = blockIdx.x;
  const int bh = blockIdx.y;
  const int b = bh >> 4, h = bh & 15;
  __shared__ float kvs[4225];
  __shared__ float kss[65];
  const int tid = threadIdx.x;
  const float* kvp = kv + (size_t)bh * 4225;
  for (int i = tid; i < 4225; i += 256) kvs[i] = kvp[i];
  if (tid < 65) kss[tid] = ksum[bh * 65 + tid];
  __syncthreads();

  const int n = nchunk * 256 + tid;
  const size_t qoff = ((size_t)(b * S_LEN + n)) * 512 + h * 32;
  float q[32], qq[32];
#pragma unroll
  for (int f4 = 0; f4 < 8; ++f4) {
    float4 v = *reinterpret_cast<const float4*>(&qbuf[qoff + f4 * 4]);
    q[f4 * 4 + 0] = v.x; qq[f4 * 4 + 0] = 0.5f * v.x * v.x;
    q[f4 * 4 + 1] = v.y; qq[f4 * 4 + 1] = 0.5f * v.y * v.y;
    q[f4 * 4 + 2] = v.z; qq[f4 * 4 + 2] = 0.5f * v.z * v.z;
    q[f4 * 4 + 3] = v.w; qq[f4 * 4 + 3] = 0.5f * v.w * v.w;
  }
  float qsum = 1.f;
#pragma unroll
  for (int f = 0; f < 32; ++f) qsum += q[f] + qq[f];
  const int m = mask[b * S_LEN + n];
  const size_t rowbase = (size_t)(b * S_LEN + n) * KPAD;
  for (int e = 0; e < 65; ++e) {
    float acc = kvs[e];
#pragma unroll
    for (int f = 0; f < 32; ++f) {
      acc += q[f] * kvs[(1 + f) * 65 + e];
      acc += qq[f] * kvs[(33 + f) * 65 + e];
    }
    float z = qsum * kss[e] + 1e-9f;
    float o = (m == 0) ? 0.f : acc / z;
    ushort_t hh, ll;
    splitf(o, hh, ll);
    ath[rowbase + h * 65 + e] = hh;
    atl[rowbase + h * 65 + e] = ll;
  }
  if (h == 15) {
#pragma unroll
    for (int p = 0; p < 16; ++p) {
      ath[rowbase + 1040 + p] = 0;
      atl[rowbase + 1040 + p] = 0;
    }
  }
}

extern "C" void kernel_launch(void* const* d_in, const int* in_sizes, int n_in,
                              void* d_out, int out_size, void* d_ws, size_t ws_size,
                              hipStream_t stream) {
  const float* hs = (const float*)d_in[0];
  const int* mask = (const int*)d_in[1];
  const float* Wq = (const float*)d_in[2];
  const float* Wk = (const float*)d_in[3];
  const float* Wv = (const float*)d_in[4];
  const float* Wo = (const float*)d_in[5];
  float* out = (float*)d_out;

  // workspace layout (bytes)
  const size_t SPLIT_SZ = (size_t)M_TOK * KPAD * 2;  // one bf16 plane: 34.6 MB
  const size_t R1 = 2 * SPLIT_SZ;                    // hs hi/lo -> later kq buf
  const size_t R2 = 2 * SPLIT_SZ;                    // vbuf (f32) / attn hi+lo
  const size_t KV_B = 64 * 4225 * 4;
  const size_t KS_B = 64 * 65 * 4;
  const size_t R3 = KV_B + KS_B + 8 * KV_B + 8 * KS_B;
  const size_t WT_SZ = (size_t)NPADW * KPAD * 2;

  char* base = (char*)d_ws;
  ushort_t* hsh = (ushort_t*)base;
  ushort_t* hsl = hsh + (size_t)M_TOK * KPAD;
  float* kqbuf = (float*)base;  // aliases hs split (used after V-GEMM)
  char* b2 = base + R1;
  float* vbuf = (float*)b2;
  ushort_t* ath = (ushort_t*)b2;  // aliases vbuf (used after kv state built)
  ushort_t* atl = ath + (size_t)M_TOK * KPAD;
  char* b3 = b2 + R2;
  float* kv = (float*)b3;
  float* ksum = kv + 64 * 4225;
  float* kvpart = ksum + 64 * 65;
  float* kspart = kvpart + 8 * 64 * 4225;
  char* b4 = b3 + R3;
  ushort_t* Wvh = (ushort_t*)b4;
  ushort_t* Wvl = Wvh + (size_t)NPADW * KPAD;
  ushort_t* Woh = Wvl + (size_t)NPADW * KPAD;
  ushort_t* Wol = Woh + (size_t)NPADW * KPAD;

  dim3 blk(256);
  const int C8 = KPAD / 8;

  // split inputs
  split_hs_kernel<<<(M_TOK * C8 + 255) / 256, blk, 0, stream>>>(hs, hsh, hsl);
  split_w_kernel<<<(NPADW * C8 + 255) / 256, blk, 0, stream>>>(Wv, Wvh, Wvl);
  split_w_kernel<<<(NPADW * C8 + 255) / 256, blk, 0, stream>>>(Wo, Woh, Wol);

  // V projection (split-bf16 MFMA)
  gemm_split<<<dim3(9, M_TOK / 128), blk, 0, stream>>>(hsh, hsl, Wvh, Wvl, vbuf, DMODEL);

  // k projection (fp32)  -- overwrites hs-split region (dead after V-GEMM)
  gemm_rr<<<dim3(512 / BN, M_TOK / BM), blk, 0, stream>>>(hs, Wk, kqbuf, M_TOK, 512, DMODEL);

  // kv state
  kv_kernel<<<dim3(64, 8), blk, 0, stream>>>(kqbuf, vbuf, kvpart, kspart);
  kv_reduce<<<dim3((64 * 4225 + 64 * 65 + 255) / 256), blk, 0, stream>>>(kvpart, kspart, kv, ksum);

  // q projection (fp32, reuses kq buffer)
  gemm_rr<<<dim3(512 / BN, M_TOK / BM), blk, 0, stream>>>(hs, Wq, kqbuf, M_TOK, 512, DMODEL);

  // attention output as split bf16 (overwrites vbuf region; v dead after kv state)
  qkv_kernel<<<dim3(16, 64), blk, 0, stream>>>(kqbuf, kv, ksum, mask, ath, atl);

  // output projection (split-bf16 MFMA)
  gemm_split<<<dim3(9, M_TOK / 128), blk, 0, stream>>>(ath, atl, Woh, Wol, out, DMODEL);
}